// Round 2
// baseline (224.997 us; speedup 1.0000x reference)
//
#include <hip/hip_runtime.h>
#include <hip/hip_bf16.h>
#include <cstdint>

#define B_ 2
#define C_ 128
#define E_ 60000

typedef unsigned int uint32_;
typedef unsigned short ushort_;
typedef float v2f __attribute__((ext_vector_type(2)));

// unpack two bf16 (dword: low = ch0, high = ch1) to packed float2
__device__ __forceinline__ v2f bp2(uint32_ v) {
    v2f r;
    r.x = __uint_as_float(v << 16);
    r.y = __uint_as_float(v & 0xffff0000u);
    return r;
}

__device__ __forceinline__ v2f vabs2(v2f a) {
    v2f r; r.x = fabsf(a.x); r.y = fabsf(a.y); return r;
}

// float -> bf16 round-to-nearest-even
__device__ __forceinline__ ushort_ f2b(float f) {
    union { float f; uint32_ u; } x; x.f = f;
    uint32_ u = x.u + 0x7fffu + ((x.u >> 16) & 1u);
    return (ushort_)(u >> 16);
}

// within-32-lane-group xor-add via ds_swizzle (and_mask 0x1F keeps halves separate)
__device__ __forceinline__ float swz_add(float v, const int pat) {
    switch (pat) {
    case 1:  return v + __int_as_float(__builtin_amdgcn_ds_swizzle(__float_as_int(v), 0x041F));
    case 2:  return v + __int_as_float(__builtin_amdgcn_ds_swizzle(__float_as_int(v), 0x081F));
    case 4:  return v + __int_as_float(__builtin_amdgcn_ds_swizzle(__float_as_int(v), 0x101F));
    case 8:  return v + __int_as_float(__builtin_amdgcn_ds_swizzle(__float_as_int(v), 0x201F));
    default: return v + __int_as_float(__builtin_amdgcn_ds_swizzle(__float_as_int(v), 0x401F));
    }
}

#define RS_ 264   // LDS row stride in ushorts (256 + 8 pad -> 2-way max on b128 reads)

// ---------------------------------------------------------------------------
// Kernel 0: prep = fuse-weight fold (blocks 0..59) + cst (block 60)
//                + transpose/quantize (blocks 61..): one block = 32 edges,
//                ALL 128 channels, BOTH tensors -> writes complete 512 B
//                records as one 16 KB contiguous burst (4 KB per wave-step).
// Read side: one thread = one full (tensor,channel) row, 32 consecutive
// floats (8x float4). Store side: fully coalesced uint4 x4 per thread.
// ---------------------------------------------------------------------------
__global__ __launch_bounds__(256) void prep_kernel(
    const float* __restrict__ x0, const float* __restrict__ x1,
    const float* __restrict__ Wa_local, const float* __restrict__ ba_local,
    const float* __restrict__ Wb_local, const float* __restrict__ bb_local,
    const float* __restrict__ Wa_tri,  const float* __restrict__ ba_tri,
    const float* __restrict__ Wb_tri,  const float* __restrict__ bb_tri,
    const float* __restrict__ Wa_fuse, const float* __restrict__ ba_fuse,
    const float* __restrict__ Wb_fuse, const float* __restrict__ bb_fuse,
    ushort_* __restrict__ xt, float* __restrict__ Vw, float* __restrict__ cst)
{
    __shared__ __align__(16) ushort_ smem_us[32 * RS_];
    const int lane = threadIdx.x & 63;
    const int wv   = threadIdx.x >> 6;

    if (blockIdx.x < 60) {
        // ---- Vw: fold 256->3 fuse conv into tri (+local at s==0) weights ----
        float* smemf = (float*)smem_us;
        const int pj    = blockIdx.x / 10;   // 0..5  (p,j)
        const int chunk = blockIdx.x % 10;   // 0..9
        const int p = pj / 3, j = pj % 3;
        const int f = chunk * 64 + lane;     // flat c*5+s
        const float* Wf = p ? Wb_fuse : Wa_fuse;   // [3][256]
        const float* Wt = p ? Wb_tri  : Wa_tri;    // [128][128][5] flat o*640+f
        const float* Wl = p ? Wb_local : Wa_local; // [128][128]
        const int o0 = wv * 32;              // each wave owns 32 of 128 o's
        float a0 = 0.f, a1 = 0.f, a2 = 0.f, a3 = 0.f;
        for (int o = o0; o < o0 + 32; o += 4) {
            a0 += Wf[j * 256 + 128 + o]     * Wt[(o)     * 640 + f];
            a1 += Wf[j * 256 + 129 + o]     * Wt[(o + 1) * 640 + f];
            a2 += Wf[j * 256 + 130 + o]     * Wt[(o + 2) * 640 + f];
            a3 += Wf[j * 256 + 131 + o]     * Wt[(o + 3) * 640 + f];
        }
        float acc = (a0 + a1) + (a2 + a3);
        const int s = f % 5, c = f / 5;
        if (s == 0) {   // absorb local conv into s=0 slot
            float b0 = 0.f, b1 = 0.f, b2 = 0.f, b3 = 0.f;
            for (int o = o0; o < o0 + 32; o += 4) {
                b0 += Wf[j * 256 + o]     * Wl[(o)     * C_ + c];
                b1 += Wf[j * 256 + o + 1] * Wl[(o + 1) * C_ + c];
                b2 += Wf[j * 256 + o + 2] * Wl[(o + 2) * C_ + c];
                b3 += Wf[j * 256 + o + 3] * Wl[(o + 3) * C_ + c];
            }
            acc += (b0 + b1) + (b2 + b3);
        }
        smemf[wv * 64 + lane] = acc;
        __syncthreads();
        if (wv == 0) {
            float tot = smemf[lane] + smemf[64 + lane] + smemf[128 + lane] + smemf[192 + lane];
            Vw[(pj * 5 + s) * C_ + c] = tot;
        }
    } else if (blockIdx.x == 60) {
        // ---- cst: one wave per output j, lanes parallel over o ----
        const int j = wv;
        if (j < 3) {
            float acc;
            {
                const int l = lane;
                acc = Wa_fuse[j * 256 + l]       * ba_local[l]
                    + Wa_fuse[j * 256 + 128 + l] * ba_tri[l]
                    + Wb_fuse[j * 256 + l]       * bb_local[l]
                    + Wb_fuse[j * 256 + 128 + l] * bb_tri[l];
            }
            {
                const int l = lane + 64;
                acc += Wa_fuse[j * 256 + l]       * ba_local[l]
                     + Wa_fuse[j * 256 + 128 + l] * ba_tri[l]
                     + Wb_fuse[j * 256 + l]       * bb_local[l]
                     + Wb_fuse[j * 256 + 128 + l] * bb_tri[l];
            }
            acc = swz_add(acc, 1); acc = swz_add(acc, 2); acc = swz_add(acc, 4);
            acc = swz_add(acc, 8); acc = swz_add(acc, 16);
            acc += __shfl_xor(acc, 32, 64);
            if (lane == 0) cst[j] = acc + ba_fuse[j] + bb_fuse[j];
        }
    } else {
        // ---- transpose + quantize: [B,C,E] f32 -> interleaved [b][e][2][C] bf16
        const int tb = blockIdx.x - 61;      // 0..3749
        const int b  = tb / 1875;
        const int bx = tb % 1875;
        const int e0 = bx * 32;
        const int t  = threadIdx.x;
        const int which = t >> 7;            // 0 -> x0, 1 -> x1
        const int c     = t & 127;
        const float* src = (which ? x1 : x0) + ((size_t)b * C_ + c) * E_ + e0;
        float4 v[8];
#pragma unroll
        for (int k = 0; k < 8; ++k) v[k] = ((const float4*)src)[k];
        // LDS column = t (== which*128 + c), rows = e. 2 lanes/dword on b16
        // writes -> 2-way (free).
#pragma unroll
        for (int k = 0; k < 8; ++k) {
            smem_us[(4 * k + 0) * RS_ + t] = f2b(v[k].x);
            smem_us[(4 * k + 1) * RS_ + t] = f2b(v[k].y);
            smem_us[(4 * k + 2) * RS_ + t] = f2b(v[k].z);
            smem_us[(4 * k + 3) * RS_ + t] = f2b(v[k].w);
        }
        __syncthreads();
        // write: thread t -> record e0+(t>>3), ushorts [(t&7)*32, +32)
        const int e  = t >> 3;
        const int u0 = (t & 7) * 32;
        const ushort_* r = smem_us + e * RS_ + u0;
        uint4 w0 = *(const uint4*)(r);
        uint4 w1 = *(const uint4*)(r + 8);
        uint4 w2 = *(const uint4*)(r + 16);
        uint4 w3 = *(const uint4*)(r + 24);
        ushort_* dst = xt + ((size_t)(b * E_ + e0 + e) << 8) + u0;
        ((uint4*)dst)[0] = w0;
        ((uint4*)dst)[1] = w1;
        ((uint4*)dst)[2] = w2;
        ((uint4*)dst)[3] = w3;
    }
}

// ---------------------------------------------------------------------------
// Kernel 1: fused gather + features + 3-channel projection.
// R2 change: sched_barrier(0) between next-pair load issue and current-pair
// compute. R1's double-buffer was DEFEATED (VGPR=72 proves cur+next never
// both live) -- the scheduler sank the prefetch to its uses. Pinning the
// order makes the compiler emit a COUNTED vmcnt wait for cur (next's 20
// loads stay in flight across the compute). VGPR should rise to ~120-140.
// ---------------------------------------------------------------------------
struct GD {
    uint32_ A0, A1, A2, A3, A4;      // edge A, x0 self+4 neighbors
    uint32_ Cc0, Cc1, Cc2, Cc3, Cc4; // edge A, x1
    uint32_ D0, D1, D2, D3, D4;      // edge B, x0
    uint32_ F0, F1, F2, F3, F4;      // edge B, x1
};

__device__ __forceinline__ GD issue_loads(const uint32_* __restrict__ xt,
                                          int pair, int4 gA, int4 gB, int lane)
{
    const int e0 = 2 * pair;
    const uint32_ badd = (e0 >= E_) ? (uint32_)E_ : 0u;
    const uint32_ sA = ((uint32_)e0 << 7) + lane;       // record = global edge id
    const uint32_ sB = sA + 128;
    const uint32_ n1 = ((badd + (uint32_)gA.x) << 7) + lane;
    const uint32_ n2 = ((badd + (uint32_)gA.y) << 7) + lane;
    const uint32_ n3 = ((badd + (uint32_)gA.z) << 7) + lane;
    const uint32_ n4 = ((badd + (uint32_)gA.w) << 7) + lane;
    const uint32_ m1 = ((badd + (uint32_)gB.x) << 7) + lane;
    const uint32_ m2 = ((badd + (uint32_)gB.y) << 7) + lane;
    const uint32_ m3 = ((badd + (uint32_)gB.z) << 7) + lane;
    const uint32_ m4 = ((badd + (uint32_)gB.w) << 7) + lane;
    GD g;
    g.A0 = xt[sA]; g.Cc0 = xt[sA + 64];
    g.A1 = xt[n1]; g.Cc1 = xt[n1 + 64];
    g.A2 = xt[n2]; g.Cc2 = xt[n2 + 64];
    g.A3 = xt[n3]; g.Cc3 = xt[n3 + 64];
    g.A4 = xt[n4]; g.Cc4 = xt[n4 + 64];
    g.D0 = xt[sB]; g.F0 = xt[sB + 64];
    g.D1 = xt[m1]; g.F1 = xt[m1 + 64];
    g.D2 = xt[m2]; g.F2 = xt[m2 + 64];
    g.D3 = xt[m3]; g.F3 = xt[m3 + 64];
    g.D4 = xt[m4]; g.F4 = xt[m4 + 64];
    return g;
}

__device__ __forceinline__ void edge3(uint32_ X0, uint32_ X1, uint32_ X2, uint32_ X3, uint32_ X4,
                                      uint32_ Y0, uint32_ Y1, uint32_ Y2, uint32_ Y3, uint32_ Y4,
                                      const v2f (*w)[3][5],
                                      float& r0, float& r1, float& r2)
{
    v2f a0 = bp2(X0), a1 = bp2(X1), a2 = bp2(X2), a3 = bp2(X3), a4 = bp2(X4);
    v2f b0 = bp2(Y0), b1 = bp2(Y1), b2 = bp2(Y2), b3 = bp2(Y3), b4 = bp2(Y4);
    v2f sa1 = a1 + a3, sa2 = a2 + a4;
    v2f da1 = vabs2(a1 - a3), da2 = vabs2(a2 - a4);
    v2f sb1 = b1 + b3, sb2 = b2 + b4;
    v2f db1 = vabs2(b1 - b3), db2 = vabs2(b2 - b4);
    v2f t0 = w[0][0][0] * a0, t1 = w[0][1][0] * a0, t2 = w[0][2][0] * a0;
    t0 += w[0][0][1] * sa1; t1 += w[0][1][1] * sa1; t2 += w[0][2][1] * sa1;
    t0 += w[0][0][2] * sa2; t1 += w[0][1][2] * sa2; t2 += w[0][2][2] * sa2;
    t0 += w[0][0][3] * da1; t1 += w[0][1][3] * da1; t2 += w[0][2][3] * da1;
    t0 += w[0][0][4] * da2; t1 += w[0][1][4] * da2; t2 += w[0][2][4] * da2;
    t0 += w[1][0][0] * b0;  t1 += w[1][1][0] * b0;  t2 += w[1][2][0] * b0;
    t0 += w[1][0][1] * sb1; t1 += w[1][1][1] * sb1; t2 += w[1][2][1] * sb1;
    t0 += w[1][0][2] * sb2; t1 += w[1][1][2] * sb2; t2 += w[1][2][2] * sb2;
    t0 += w[1][0][3] * db1; t1 += w[1][1][3] * db1; t2 += w[1][2][3] * db1;
    t0 += w[1][0][4] * db2; t1 += w[1][1][4] * db2; t2 += w[1][2][4] * db2;
    r0 = t0.x + t0.y; r1 = t1.x + t1.y; r2 = t2.x + t2.y;
}

__global__ __launch_bounds__(256, 3) void mesh_fused_kernel(
    const uint32_* __restrict__ xt, const int* __restrict__ gemm,
    const float* __restrict__ Vw, const float* __restrict__ cst,
    float* __restrict__ out)
{
    const int lane = threadIdx.x & 63;
    const int wv   = threadIdx.x >> 6;
    const int gw   = blockIdx.x * 4 + wv;
    const int nw   = gridDim.x * 4;

    v2f w[2][3][5];
#pragma unroll
    for (int p = 0; p < 2; ++p)
#pragma unroll
        for (int j = 0; j < 3; ++j)
#pragma unroll
            for (int s = 0; s < 5; ++s)
                w[p][j][s] = *(const v2f*)(Vw + (((p * 3 + j) * 5 + s) << 7) + lane * 2);

    const int  jj     = lane >> 4;                 // 0..3
    const bool is0    = (jj == 0), is1 = (jj == 1);
    const bool writer = ((lane & 15) == 0) && (jj < 3);
    const float cj    = is0 ? cst[0] : (is1 ? cst[1] : cst[2]);
    float* obase      = out + (size_t)(jj < 3 ? jj : 2) * E_;

    const int4* g4 = (const int4*)gemm;
    const int npair = (B_ * E_) / 2;               // gw < npair always (nw<=8192)

    // ---- double-buffer prologue ----
    int pnext = (gw + nw < npair) ? gw + nw : gw;
    int4 giA = g4[2 * gw], giB = g4[2 * gw + 1];
    GD cur = issue_loads(xt, gw, giA, giB, lane);  // pair 0 data in flight
    int4 niA = g4[2 * pnext], niB = g4[2 * pnext + 1];   // next indices in flight

#pragma unroll 2
    for (int pair = gw; pair < npair; pair += nw) {
        // issue NEXT pair's 20 gathers before touching current data
        GD nb = issue_loads(xt, pnext, niA, niB, lane);
        const int p2 = (pnext + nw < npair) ? pnext + nw : pnext;
        niA = g4[2 * p2]; niB = g4[2 * p2 + 1];

        // pin order: nothing below may be hoisted above the prefetch issue,
        // and the prefetch may not sink into the compute.
        __builtin_amdgcn_sched_barrier(0);

        // ---- compute on current (counted vmcnt leaves nb's 20 in flight) ----
        float rA0, rA1, rA2, rB0, rB1, rB2;
        edge3(cur.A0, cur.A1, cur.A2, cur.A3, cur.A4,
              cur.Cc0, cur.Cc1, cur.Cc2, cur.Cc3, cur.Cc4, w, rA0, rA1, rA2);
        edge3(cur.D0, cur.D1, cur.D2, cur.D3, cur.D4,
              cur.F0, cur.F1, cur.F2, cur.F3, cur.F4, w, rB0, rB1, rB2);

        // partial reduce (independent A/B chains interleaved for pipe overlap)
        rA0 = swz_add(rA0, 16); rB0 = swz_add(rB0, 16);
        rA1 = swz_add(rA1, 16); rB1 = swz_add(rB1, 16);
        rA2 = swz_add(rA2, 16); rB2 = swz_add(rB2, 16);
        rA0 += __shfl_xor(rA0, 32, 64); rB0 += __shfl_xor(rB0, 32, 64);
        rA1 += __shfl_xor(rA1, 32, 64); rB1 += __shfl_xor(rB1, 32, 64);
        rA2 += __shfl_xor(rA2, 32, 64); rB2 += __shfl_xor(rB2, 32, 64);

        float vA = is0 ? rA0 : (is1 ? rA1 : rA2);
        float vB = is0 ? rB0 : (is1 ? rB1 : rB2);
        vA = swz_add(vA, 1); vB = swz_add(vB, 1);
        vA = swz_add(vA, 2); vB = swz_add(vB, 2);
        vA = swz_add(vA, 4); vB = swz_add(vB, 4);
        vA = swz_add(vA, 8); vB = swz_add(vB, 8);

        if (writer) {
            const int e0p = 2 * pair;
            const int bb  = (e0p >= E_) ? 1 : 0;
            const int ee  = e0p - (bb ? E_ : 0);
            float2 st; st.x = vA + cj; st.y = vB + cj;
            *(float2*)(obase + (bb ? 3 * E_ : 0) + ee) = st;   // ee even -> aligned
        }

        cur = nb;        // rotated away by unroll-2
        pnext = p2;
    }
}

extern "C" void kernel_launch(void* const* d_in, const int* in_sizes, int n_in,
                              void* d_out, int out_size, void* d_ws, size_t ws_size,
                              hipStream_t stream) {
    const float* x0       = (const float*)d_in[0];
    const float* x1       = (const float*)d_in[1];
    const int*   gemm     = (const int*)d_in[2];
    const float* Wa_local = (const float*)d_in[3];
    const float* ba_local = (const float*)d_in[4];
    const float* Wb_local = (const float*)d_in[5];
    const float* bb_local = (const float*)d_in[6];
    const float* Wa_tri   = (const float*)d_in[7];
    const float* ba_tri   = (const float*)d_in[8];
    const float* Wb_tri   = (const float*)d_in[9];
    const float* bb_tri   = (const float*)d_in[10];
    const float* Wa_fuse  = (const float*)d_in[11];
    const float* ba_fuse  = (const float*)d_in[12];
    const float* Wb_fuse  = (const float*)d_in[13];
    const float* bb_fuse  = (const float*)d_in[14];
    float* out = (float*)d_out;

    ushort_* xt  = (ushort_*)d_ws;                       // [B][E][2][C] bf16
    float*   Vw  = (float*)(xt + (size_t)B_ * E_ * 2 * C_);
    float*   cst = Vw + 2 * 3 * 5 * C_;

    hipLaunchKernelGGL(prep_kernel, dim3(61 + 2 * (E_ / 32)), dim3(256), 0, stream,
                       x0, x1,
                       Wa_local, ba_local, Wb_local, bb_local,
                       Wa_tri, ba_tri, Wb_tri, bb_tri,
                       Wa_fuse, ba_fuse, Wb_fuse, bb_fuse, xt, Vw, cst);

    hipLaunchKernelGGL(mesh_fused_kernel, dim3(2048), dim3(256), 0, stream,
                       (const uint32_*)xt, gemm, Vw, cst, out);
}

// Round 3
// 218.372 us; speedup vs baseline: 1.0303x; 1.0303x over previous
//
#include <hip/hip_runtime.h>
#include <hip/hip_bf16.h>
#include <cstdint>

#define B_ 2
#define C_ 128
#define E_ 60000

typedef unsigned int uint32_;
typedef unsigned short ushort_;
typedef float v2f __attribute__((ext_vector_type(2)));

// unpack two bf16 (dword: low = ch0, high = ch1) to packed float2
__device__ __forceinline__ v2f bp2(uint32_ v) {
    v2f r;
    r.x = __uint_as_float(v << 16);
    r.y = __uint_as_float(v & 0xffff0000u);
    return r;
}

__device__ __forceinline__ v2f vabs2(v2f a) {
    v2f r; r.x = fabsf(a.x); r.y = fabsf(a.y); return r;
}

// float -> bf16 round-to-nearest-even
__device__ __forceinline__ ushort_ f2b(float f) {
    union { float f; uint32_ u; } x; x.f = f;
    uint32_ u = x.u + 0x7fffu + ((x.u >> 16) & 1u);
    return (ushort_)(u >> 16);
}

// within-32-lane-group xor-add via ds_swizzle (and_mask 0x1F keeps halves separate)
__device__ __forceinline__ float swz_add(float v, const int pat) {
    switch (pat) {
    case 1:  return v + __int_as_float(__builtin_amdgcn_ds_swizzle(__float_as_int(v), 0x041F));
    case 2:  return v + __int_as_float(__builtin_amdgcn_ds_swizzle(__float_as_int(v), 0x081F));
    case 4:  return v + __int_as_float(__builtin_amdgcn_ds_swizzle(__float_as_int(v), 0x101F));
    case 8:  return v + __int_as_float(__builtin_amdgcn_ds_swizzle(__float_as_int(v), 0x201F));
    default: return v + __int_as_float(__builtin_amdgcn_ds_swizzle(__float_as_int(v), 0x401F));
    }
}

// ---------------------------------------------------------------------------
// Kernel 0: prep = fuse-weight fold (blocks 0..59) + cst (block 60)
//                + transpose/quantize (blocks 61..) -- R1-proven structure
//                (R2's 256-stream read pattern regressed 50->58us; reverted).
// NEW dst layout (channel-SPLIT for L2 capacity): two arrays of 256 B records
//   xt_lo = [b][e][{x0,x1}][ch 0..63]  bf16   (30.7 MB)
//   xt_hi = [b][e][{x0,x1}][ch 64..127] bf16  (30.7 MB)
// Each fits the 32 MB aggregate L2 during its gather pass.
// ---------------------------------------------------------------------------
__global__ __launch_bounds__(256) void prep_kernel(
    const float* __restrict__ x0, const float* __restrict__ x1,
    const float* __restrict__ Wa_local, const float* __restrict__ ba_local,
    const float* __restrict__ Wb_local, const float* __restrict__ bb_local,
    const float* __restrict__ Wa_tri,  const float* __restrict__ ba_tri,
    const float* __restrict__ Wb_tri,  const float* __restrict__ bb_tri,
    const float* __restrict__ Wa_fuse, const float* __restrict__ ba_fuse,
    const float* __restrict__ Wb_fuse, const float* __restrict__ bb_fuse,
    ushort_* __restrict__ xt_lo, ushort_* __restrict__ xt_hi,
    float* __restrict__ Vw, float* __restrict__ cst)
{
    __shared__ float smem[32 * 65];          // transpose tile; reused as reduce buf
    const int lane = threadIdx.x & 63;
    const int wv   = threadIdx.x >> 6;

    if (blockIdx.x < 60) {
        // ---- Vw: fold 256->3 fuse conv into tri (+local at s==0) weights ----
        const int pj    = blockIdx.x / 10;   // 0..5  (p,j)
        const int chunk = blockIdx.x % 10;   // 0..9
        const int p = pj / 3, j = pj % 3;
        const int f = chunk * 64 + lane;     // flat c*5+s
        const float* Wf = p ? Wb_fuse : Wa_fuse;   // [3][256]
        const float* Wt = p ? Wb_tri  : Wa_tri;    // [128][128][5] flat o*640+f
        const float* Wl = p ? Wb_local : Wa_local; // [128][128]
        const int o0 = wv * 32;              // each wave owns 32 of 128 o's
        float a0 = 0.f, a1 = 0.f, a2 = 0.f, a3 = 0.f;
        for (int o = o0; o < o0 + 32; o += 4) {
            a0 += Wf[j * 256 + 128 + o]     * Wt[(o)     * 640 + f];
            a1 += Wf[j * 256 + 129 + o]     * Wt[(o + 1) * 640 + f];
            a2 += Wf[j * 256 + 130 + o]     * Wt[(o + 2) * 640 + f];
            a3 += Wf[j * 256 + 131 + o]     * Wt[(o + 3) * 640 + f];
        }
        float acc = (a0 + a1) + (a2 + a3);
        const int s = f % 5, c = f / 5;
        if (s == 0) {   // absorb local conv into s=0 slot
            float b0 = 0.f, b1 = 0.f, b2 = 0.f, b3 = 0.f;
            for (int o = o0; o < o0 + 32; o += 4) {
                b0 += Wf[j * 256 + o]     * Wl[(o)     * C_ + c];
                b1 += Wf[j * 256 + o + 1] * Wl[(o + 1) * C_ + c];
                b2 += Wf[j * 256 + o + 2] * Wl[(o + 2) * C_ + c];
                b3 += Wf[j * 256 + o + 3] * Wl[(o + 3) * C_ + c];
            }
            acc += (b0 + b1) + (b2 + b3);
        }
        smem[wv * 64 + lane] = acc;
        __syncthreads();
        if (wv == 0) {
            float tot = smem[lane] + smem[64 + lane] + smem[128 + lane] + smem[192 + lane];
            Vw[(pj * 5 + s) * C_ + c] = tot;
        }
    } else if (blockIdx.x == 60) {
        // ---- cst: one wave per output j, lanes parallel over o ----
        const int j = wv;
        if (j < 3) {
            float acc;
            {
                const int l = lane;
                acc = Wa_fuse[j * 256 + l]       * ba_local[l]
                    + Wa_fuse[j * 256 + 128 + l] * ba_tri[l]
                    + Wb_fuse[j * 256 + l]       * bb_local[l]
                    + Wb_fuse[j * 256 + 128 + l] * bb_tri[l];
            }
            {
                const int l = lane + 64;
                acc += Wa_fuse[j * 256 + l]       * ba_local[l]
                     + Wa_fuse[j * 256 + 128 + l] * ba_tri[l]
                     + Wb_fuse[j * 256 + l]       * bb_local[l]
                     + Wb_fuse[j * 256 + 128 + l] * bb_tri[l];
            }
            acc = swz_add(acc, 1); acc = swz_add(acc, 2); acc = swz_add(acc, 4);
            acc = swz_add(acc, 8); acc = swz_add(acc, 16);
            acc += __shfl_xor(acc, 32, 64);
            if (lane == 0) cst[j] = acc + ba_fuse[j] + bb_fuse[j];
        }
    } else {
        // ---- transpose + quantize (R1 structure): [B,C,E] f32 -> split bf16
        const int tb = blockIdx.x - 61;      // 0..14999
        const int bx = tb % 1875;            // e-tile (32 edges)
        const int rz = tb / 1875;            // 0..7
        const int by = rz & 1;               // channel half (64 ch)
        const int bz = rz >> 1;              // 0..3
        const int which = bz >> 1;           // 0 -> x0, 1 -> x1
        const int b     = bz & 1;
        const float* src = (which ? x1 : x0) + (size_t)b * C_ * E_;
        ushort_* half_base = by ? xt_hi : xt_lo;
        const int e0 = bx * 32;
        const int c0 = by * 64;
        const int t  = threadIdx.x;
        float (*tile)[65] = (float(*)[65])smem;
        {
            const int c  = t >> 2;          // 0..63
            const int e8 = (t & 3) * 8;     // 0,8,16,24
            const float* pp = src + (size_t)(c0 + c) * E_ + e0 + e8;
            float4 v0 = *(const float4*)pp;
            float4 v1 = *(const float4*)(pp + 4);
            tile[e8 + 0][c] = v0.x; tile[e8 + 1][c] = v0.y;
            tile[e8 + 2][c] = v0.z; tile[e8 + 3][c] = v0.w;
            tile[e8 + 4][c] = v1.x; tile[e8 + 5][c] = v1.y;
            tile[e8 + 6][c] = v1.z; tile[e8 + 7][c] = v1.w;
        }
        __syncthreads();
        {
            const int e  = t >> 3;          // 0..31
            const int c8 = (t & 7) * 8;     // 0..56 (local ch within the half)
            const float* r = &tile[e][c8];
            uint32_ w0 = (uint32_)f2b(r[0]) | ((uint32_)f2b(r[1]) << 16);
            uint32_ w1 = (uint32_)f2b(r[2]) | ((uint32_)f2b(r[3]) << 16);
            uint32_ w2 = (uint32_)f2b(r[4]) | ((uint32_)f2b(r[5]) << 16);
            uint32_ w3 = (uint32_)f2b(r[6]) | ((uint32_)f2b(r[7]) << 16);
            uint4 w; w.x = w0; w.y = w1; w.z = w2; w.w = w3;
            // record = [2 tensors][64 ch] = 128 ushorts
            const size_t rec = (size_t)(b * E_ + e0 + e) * 2 + which;
            *(uint4*)(half_base + (rec << 6) + c8) = w;
        }
    }
}

// ---------------------------------------------------------------------------
// Kernel 1: half-channel gather pass. Record = 256 B = one wave-load.
// Lane l holds 2 channels of ONE tensor (p = l>>5, ch = 2*(l&31)+{0,1}+coff).
// 4 edges per iteration -> 20 gathers in flight. Full-wave reduce sums over
// both tensors and the 64 channels of this pass.
// pass 1 (finalp=0): out = partial.  pass 2 (finalp=1): out += partial + cst.
// Theory: per-pass working set 30.7 MB <= 32 MB aggregate L2 -> gathers
// become L2 hits (measured R0-R2 hit rate tracked cache/working-set).
// ---------------------------------------------------------------------------
__global__ __launch_bounds__(256, 3) void mesh_half_kernel(
    const uint32_* __restrict__ xh, const int* __restrict__ gemm,
    const float* __restrict__ Vw, const float* __restrict__ cst,
    float* __restrict__ out, const int coff, const int finalp)
{
    const int lane = threadIdx.x & 63;
    const int wv   = threadIdx.x >> 6;
    const int gw   = blockIdx.x * 4 + wv;
    const int nw   = gridDim.x * 4;

    const int p = lane >> 5;                 // tensor this lane handles
    v2f w[3][5];
#pragma unroll
    for (int j = 0; j < 3; ++j)
#pragma unroll
        for (int s = 0; s < 5; ++s)
            w[j][s] = *(const v2f*)(Vw + ((p * 3 + j) * 5 + s) * C_ + coff + (lane & 31) * 2);

    const int  jj     = lane >> 4;                 // 0..3
    const bool is0    = (jj == 0), is1 = (jj == 1);
    const bool writer = ((lane & 15) == 0) && (jj < 3);
    const float cj    = is0 ? cst[0] : (is1 ? cst[1] : cst[2]);
    float* obase      = out + (size_t)(jj < 3 ? jj : 2) * E_;

    const int4* g4 = (const int4*)gemm;
    const int nquad = (B_ * E_) / 4;         // 30000; gw < nquad (nw <= 8192)

    for (int q = gw; q < nquad; q += nw) {
        const int e0g = 4 * q;                         // global edge id base
        const int b   = (e0g >= E_) ? 1 : 0;
        const uint32_ badd = b ? (uint32_)E_ : 0u;

        const int4 g0 = g4[e0g], g1 = g4[e0g + 1], g2 = g4[e0g + 2], g3 = g4[e0g + 3];

        // 4 self + 16 neighbor gathers (each = 64 contiguous dwords/wave)
        uint32_ S[4], N1[4], N2[4], N3[4], N4[4];
#pragma unroll
        for (int k = 0; k < 4; ++k)
            S[k] = xh[(((uint32_)(e0g + k)) << 6) + lane];
        N1[0] = xh[((badd + (uint32_)g0.x) << 6) + lane];
        N2[0] = xh[((badd + (uint32_)g0.y) << 6) + lane];
        N3[0] = xh[((badd + (uint32_)g0.z) << 6) + lane];
        N4[0] = xh[((badd + (uint32_)g0.w) << 6) + lane];
        N1[1] = xh[((badd + (uint32_)g1.x) << 6) + lane];
        N2[1] = xh[((badd + (uint32_)g1.y) << 6) + lane];
        N3[1] = xh[((badd + (uint32_)g1.z) << 6) + lane];
        N4[1] = xh[((badd + (uint32_)g1.w) << 6) + lane];
        N1[2] = xh[((badd + (uint32_)g2.x) << 6) + lane];
        N2[2] = xh[((badd + (uint32_)g2.y) << 6) + lane];
        N3[2] = xh[((badd + (uint32_)g2.z) << 6) + lane];
        N4[2] = xh[((badd + (uint32_)g2.w) << 6) + lane];
        N1[3] = xh[((badd + (uint32_)g3.x) << 6) + lane];
        N2[3] = xh[((badd + (uint32_)g3.y) << 6) + lane];
        N3[3] = xh[((badd + (uint32_)g3.z) << 6) + lane];
        N4[3] = xh[((badd + (uint32_)g3.w) << 6) + lane];

        float r0[4], r1[4], r2[4];
#pragma unroll
        for (int k = 0; k < 4; ++k) {
            v2f a0 = bp2(S[k]);
            v2f a1 = bp2(N1[k]), a2 = bp2(N2[k]), a3 = bp2(N3[k]), a4 = bp2(N4[k]);
            v2f s1 = a1 + a3, s2 = a2 + a4;
            v2f d1 = vabs2(a1 - a3), d2 = vabs2(a2 - a4);
            v2f t0 = w[0][0] * a0, t1 = w[1][0] * a0, t2 = w[2][0] * a0;
            t0 += w[0][1] * s1; t1 += w[1][1] * s1; t2 += w[2][1] * s1;
            t0 += w[0][2] * s2; t1 += w[1][2] * s2; t2 += w[2][2] * s2;
            t0 += w[0][3] * d1; t1 += w[1][3] * d1; t2 += w[2][3] * d1;
            t0 += w[0][4] * d2; t1 += w[1][4] * d2; t2 += w[2][4] * d2;
            r0[k] = t0.x + t0.y; r1[k] = t1.x + t1.y; r2[k] = t2.x + t2.y;
        }

        // full 64-lane sum of each of the 12 values (two-stage: fold to 16-group)
#pragma unroll
        for (int k = 0; k < 4; ++k) {
            r0[k] = swz_add(r0[k], 16); r1[k] = swz_add(r1[k], 16); r2[k] = swz_add(r2[k], 16);
            r0[k] += __shfl_xor(r0[k], 32, 64);
            r1[k] += __shfl_xor(r1[k], 32, 64);
            r2[k] += __shfl_xor(r2[k], 32, 64);
        }
        float v0 = is0 ? r0[0] : (is1 ? r1[0] : r2[0]);
        float v1 = is0 ? r0[1] : (is1 ? r1[1] : r2[1]);
        float v2 = is0 ? r0[2] : (is1 ? r1[2] : r2[2]);
        float v3 = is0 ? r0[3] : (is1 ? r1[3] : r2[3]);
        v0 = swz_add(v0, 1); v1 = swz_add(v1, 1); v2 = swz_add(v2, 1); v3 = swz_add(v3, 1);
        v0 = swz_add(v0, 2); v1 = swz_add(v1, 2); v2 = swz_add(v2, 2); v3 = swz_add(v3, 2);
        v0 = swz_add(v0, 4); v1 = swz_add(v1, 4); v2 = swz_add(v2, 4); v3 = swz_add(v3, 4);
        v0 = swz_add(v0, 8); v1 = swz_add(v1, 8); v2 = swz_add(v2, 8); v3 = swz_add(v3, 8);

        if (writer) {
            const int el = e0g - (int)badd;            // local e, 4-aligned
            float* dst = obase + (b ? 3 * E_ : 0) + el;
            float4 st;
            if (finalp) {
                float4 old = *(const float4*)dst;
                st.x = old.x + v0 + cj; st.y = old.y + v1 + cj;
                st.z = old.z + v2 + cj; st.w = old.w + v3 + cj;
            } else {
                st.x = v0; st.y = v1; st.z = v2; st.w = v3;
            }
            *(float4*)dst = st;
        }
    }
}

extern "C" void kernel_launch(void* const* d_in, const int* in_sizes, int n_in,
                              void* d_out, int out_size, void* d_ws, size_t ws_size,
                              hipStream_t stream) {
    const float* x0       = (const float*)d_in[0];
    const float* x1       = (const float*)d_in[1];
    const int*   gemm     = (const int*)d_in[2];
    const float* Wa_local = (const float*)d_in[3];
    const float* ba_local = (const float*)d_in[4];
    const float* Wb_local = (const float*)d_in[5];
    const float* bb_local = (const float*)d_in[6];
    const float* Wa_tri   = (const float*)d_in[7];
    const float* ba_tri   = (const float*)d_in[8];
    const float* Wb_tri   = (const float*)d_in[9];
    const float* bb_tri   = (const float*)d_in[10];
    const float* Wa_fuse  = (const float*)d_in[11];
    const float* ba_fuse  = (const float*)d_in[12];
    const float* Wb_fuse  = (const float*)d_in[13];
    const float* bb_fuse  = (const float*)d_in[14];
    float* out = (float*)d_out;

    ushort_* xt_lo = (ushort_*)d_ws;                        // [B][E][2][64] bf16
    ushort_* xt_hi = xt_lo + (size_t)B_ * E_ * 128;         // [B][E][2][64] bf16
    float*   Vw    = (float*)(xt_hi + (size_t)B_ * E_ * 128);
    float*   cst   = Vw + 2 * 3 * 5 * C_;

    hipLaunchKernelGGL(prep_kernel, dim3(61 + 8 * (E_ / 32)), dim3(256), 0, stream,
                       x0, x1,
                       Wa_local, ba_local, Wb_local, bb_local,
                       Wa_tri, ba_tri, Wb_tri, bb_tri,
                       Wa_fuse, ba_fuse, Wb_fuse, bb_fuse, xt_lo, xt_hi, Vw, cst);

    hipLaunchKernelGGL(mesh_half_kernel, dim3(2048), dim3(256), 0, stream,
                       (const uint32_*)xt_lo, gemm, Vw, cst, out, 0, 0);
    hipLaunchKernelGGL(mesh_half_kernel, dim3(2048), dim3(256), 0, stream,
                       (const uint32_*)xt_hi, gemm, Vw, cst, out, 64, 1);
}

// Round 4
// 213.558 us; speedup vs baseline: 1.0536x; 1.0225x over previous
//
#include <hip/hip_runtime.h>
#include <hip/hip_bf16.h>
#include <cstdint>

#define B_ 2
#define C_ 128
#define E_ 60000

typedef unsigned int uint32_;
typedef unsigned short ushort_;
typedef float v2f __attribute__((ext_vector_type(2)));
typedef float v4f __attribute__((ext_vector_type(4)));

// unpack two bf16 (dword: low = ch0, high = ch1) to packed float2
__device__ __forceinline__ v2f bp2(uint32_ v) {
    v2f r;
    r.x = __uint_as_float(v << 16);
    r.y = __uint_as_float(v & 0xffff0000u);
    return r;
}

// unpack 4 bf16 from a uint2 (channel order: x.lo, x.hi, y.lo, y.hi)
__device__ __forceinline__ v4f bp4(uint2 v) {
    v4f r;
    r.x = __uint_as_float(v.x << 16);
    r.y = __uint_as_float(v.x & 0xffff0000u);
    r.z = __uint_as_float(v.y << 16);
    r.w = __uint_as_float(v.y & 0xffff0000u);
    return r;
}

__device__ __forceinline__ v4f vabs4(v4f a) {
    v4f r; r.x = fabsf(a.x); r.y = fabsf(a.y); r.z = fabsf(a.z); r.w = fabsf(a.w);
    return r;
}

// float -> bf16 round-to-nearest-even
__device__ __forceinline__ ushort_ f2b(float f) {
    union { float f; uint32_ u; } x; x.f = f;
    uint32_ u = x.u + 0x7fffu + ((x.u >> 16) & 1u);
    return (ushort_)(u >> 16);
}

// within-32-lane-group xor-add via ds_swizzle (and_mask 0x1F keeps halves separate)
__device__ __forceinline__ float swz_add(float v, const int pat) {
    switch (pat) {
    case 1:  return v + __int_as_float(__builtin_amdgcn_ds_swizzle(__float_as_int(v), 0x041F));
    case 2:  return v + __int_as_float(__builtin_amdgcn_ds_swizzle(__float_as_int(v), 0x081F));
    case 4:  return v + __int_as_float(__builtin_amdgcn_ds_swizzle(__float_as_int(v), 0x101F));
    case 8:  return v + __int_as_float(__builtin_amdgcn_ds_swizzle(__float_as_int(v), 0x201F));
    default: return v + __int_as_float(__builtin_amdgcn_ds_swizzle(__float_as_int(v), 0x401F));
    }
}

// ---------------------------------------------------------------------------
// Kernel 0: prep = fuse-weight fold (blocks 0..59) + cst (block 60)
//                + transpose/quantize (blocks 61..) -- the R1-proven structure.
// xt layout: [b][e][{x0,x1}][128ch] bf16 -> one 512 B record per edge
// (dwords 0..63 = x0 channel pairs, 64..127 = x1 channel pairs).
// ---------------------------------------------------------------------------
__global__ __launch_bounds__(256) void prep_kernel(
    const float* __restrict__ x0, const float* __restrict__ x1,
    const float* __restrict__ Wa_local, const float* __restrict__ ba_local,
    const float* __restrict__ Wb_local, const float* __restrict__ bb_local,
    const float* __restrict__ Wa_tri,  const float* __restrict__ ba_tri,
    const float* __restrict__ Wb_tri,  const float* __restrict__ bb_tri,
    const float* __restrict__ Wa_fuse, const float* __restrict__ ba_fuse,
    const float* __restrict__ Wb_fuse, const float* __restrict__ bb_fuse,
    ushort_* __restrict__ xt, float* __restrict__ Vw, float* __restrict__ cst)
{
    __shared__ float smem[32 * 65];          // transpose tile; reused as reduce buf
    const int lane = threadIdx.x & 63;
    const int wv   = threadIdx.x >> 6;

    if (blockIdx.x < 60) {
        // ---- Vw: fold 256->3 fuse conv into tri (+local at s==0) weights ----
        const int pj    = blockIdx.x / 10;   // 0..5  (p,j)
        const int chunk = blockIdx.x % 10;   // 0..9
        const int p = pj / 3, j = pj % 3;
        const int f = chunk * 64 + lane;     // flat c*5+s
        const float* Wf = p ? Wb_fuse : Wa_fuse;   // [3][256]
        const float* Wt = p ? Wb_tri  : Wa_tri;    // [128][128][5] flat o*640+f
        const float* Wl = p ? Wb_local : Wa_local; // [128][128]
        const int o0 = wv * 32;              // each wave owns 32 of 128 o's
        float a0 = 0.f, a1 = 0.f, a2 = 0.f, a3 = 0.f;
        for (int o = o0; o < o0 + 32; o += 4) {
            a0 += Wf[j * 256 + 128 + o]     * Wt[(o)     * 640 + f];
            a1 += Wf[j * 256 + 129 + o]     * Wt[(o + 1) * 640 + f];
            a2 += Wf[j * 256 + 130 + o]     * Wt[(o + 2) * 640 + f];
            a3 += Wf[j * 256 + 131 + o]     * Wt[(o + 3) * 640 + f];
        }
        float acc = (a0 + a1) + (a2 + a3);
        const int s = f % 5, c = f / 5;
        if (s == 0) {   // absorb local conv into s=0 slot
            float b0 = 0.f, b1 = 0.f, b2 = 0.f, b3 = 0.f;
            for (int o = o0; o < o0 + 32; o += 4) {
                b0 += Wf[j * 256 + o]     * Wl[(o)     * C_ + c];
                b1 += Wf[j * 256 + o + 1] * Wl[(o + 1) * C_ + c];
                b2 += Wf[j * 256 + o + 2] * Wl[(o + 2) * C_ + c];
                b3 += Wf[j * 256 + o + 3] * Wl[(o + 3) * C_ + c];
            }
            acc += (b0 + b1) + (b2 + b3);
        }
        smem[wv * 64 + lane] = acc;
        __syncthreads();
        if (wv == 0) {
            float tot = smem[lane] + smem[64 + lane] + smem[128 + lane] + smem[192 + lane];
            Vw[(pj * 5 + s) * C_ + c] = tot;
        }
    } else if (blockIdx.x == 60) {
        // ---- cst: one wave per output j, lanes parallel over o ----
        const int j = wv;
        if (j < 3) {
            float acc;
            {
                const int l = lane;
                acc = Wa_fuse[j * 256 + l]       * ba_local[l]
                    + Wa_fuse[j * 256 + 128 + l] * ba_tri[l]
                    + Wb_fuse[j * 256 + l]       * bb_local[l]
                    + Wb_fuse[j * 256 + 128 + l] * bb_tri[l];
            }
            {
                const int l = lane + 64;
                acc += Wa_fuse[j * 256 + l]       * ba_local[l]
                     + Wa_fuse[j * 256 + 128 + l] * ba_tri[l]
                     + Wb_fuse[j * 256 + l]       * bb_local[l]
                     + Wb_fuse[j * 256 + 128 + l] * bb_tri[l];
            }
            acc = swz_add(acc, 1); acc = swz_add(acc, 2); acc = swz_add(acc, 4);
            acc = swz_add(acc, 8); acc = swz_add(acc, 16);
            acc += __shfl_xor(acc, 32, 64);
            if (lane == 0) cst[j] = acc + ba_fuse[j] + bb_fuse[j];
        }
    } else {
        // ---- transpose + quantize: [B,C,E] f32 -> interleaved [b][e][2][C] bf16
        const int tb = blockIdx.x - 61;      // 0..14999
        const int bx = tb % 1875;            // e-tile (32 edges)
        const int rz = tb / 1875;            // 0..7
        const int by = rz & 1;               // channel half (64 ch)
        const int bz = rz >> 1;              // 0..3
        const int which = bz >> 1;           // 0 -> x0, 1 -> x1
        const int b     = bz & 1;
        const float* src = (which ? x1 : x0) + (size_t)b * C_ * E_;
        const int e0 = bx * 32;
        const int c0 = by * 64;
        const int t  = threadIdx.x;
        float (*tile)[65] = (float(*)[65])smem;
        {
            const int c  = t >> 2;          // 0..63
            const int e8 = (t & 3) * 8;     // 0,8,16,24
            const float* pp = src + (size_t)(c0 + c) * E_ + e0 + e8;
            float4 v0 = *(const float4*)pp;
            float4 v1 = *(const float4*)(pp + 4);
            tile[e8 + 0][c] = v0.x; tile[e8 + 1][c] = v0.y;
            tile[e8 + 2][c] = v0.z; tile[e8 + 3][c] = v0.w;
            tile[e8 + 4][c] = v1.x; tile[e8 + 5][c] = v1.y;
            tile[e8 + 6][c] = v1.z; tile[e8 + 7][c] = v1.w;
        }
        __syncthreads();
        {
            const int e  = t >> 3;          // 0..31
            const int c8 = (t & 7) * 8;     // 0..56
            const float* r = &tile[e][c8];
            uint32_ w0 = (uint32_)f2b(r[0]) | ((uint32_)f2b(r[1]) << 16);
            uint32_ w1 = (uint32_)f2b(r[2]) | ((uint32_)f2b(r[3]) << 16);
            uint32_ w2 = (uint32_)f2b(r[4]) | ((uint32_)f2b(r[5]) << 16);
            uint32_ w3 = (uint32_)f2b(r[6]) | ((uint32_)f2b(r[7]) << 16);
            uint4 w; w.x = w0; w.y = w1; w.z = w2; w.w = w3;
            const size_t rec = (size_t)((b * E_ + e0 + e) * 2 + which);
            *(uint4*)(xt + (rec << 7) + c0 + c8) = w;
        }
    }
}

// ---------------------------------------------------------------------------
// Kernel 1: fused gather + features + 3-channel projection. WIDE-GATHER form.
// R4 change: one record (512 B) = ONE global_load_dwordx2 across the wave
// (64 lanes x 8 B). 5 loads/edge instead of 20 x dword. Same bytes, 4x fewer
// vector-memory instructions. Lane l owns 4 channels of tensor p=(l>>5):
// ch 4*(l&31)..+3. A/B test for the "request-rate-limited" theory: if dur
// drops to ~30us the gather path was instruction-rate-bound; if flat it is
// line-rate-bound and further gather tuning is pointless.
// ---------------------------------------------------------------------------
__global__ __launch_bounds__(256, 4) void mesh_fused_kernel(
    const uint2* __restrict__ xt2, const int* __restrict__ gemm,
    const float* __restrict__ Vw, const float* __restrict__ cst,
    float* __restrict__ out)
{
    const int lane = threadIdx.x & 63;
    const int wv   = threadIdx.x >> 6;
    const int gw   = blockIdx.x * 4 + wv;
    const int nw   = gridDim.x * 4;

    const int p  = lane >> 5;          // tensor this lane handles
    const int c4 = (lane & 31) * 4;    // first of 4 channels this lane handles
    v4f w[3][5];
#pragma unroll
    for (int j = 0; j < 3; ++j)
#pragma unroll
        for (int s = 0; s < 5; ++s)
            w[j][s] = *(const v4f*)(Vw + ((p * 3 + j) * 5 + s) * C_ + c4);

    const int  jj     = lane >> 4;                 // 0..3
    const bool is0    = (jj == 0), is1 = (jj == 1);
    const bool writer = ((lane & 15) == 0) && (jj < 3);
    const float cj    = is0 ? cst[0] : (is1 ? cst[1] : cst[2]);
    float* obase      = out + (size_t)(jj < 3 ? jj : 2) * E_;

    const int4* g4 = (const int4*)gemm;
    const int npair = (B_ * E_) / 2;               // gw < npair (nw <= 8192)

    int4 giA = g4[2 * gw], giB = g4[2 * gw + 1];   // index prefetch (R0-proven)

    for (int pair = gw; pair < npair; pair += nw) {
        const int nxt = pair + nw;
        const int4 gA = giA, gB = giB;
        if (nxt < npair) { giA = g4[2 * nxt]; giB = g4[2 * nxt + 1]; }

        const int e0 = 2 * pair;                   // global edge id of edge A
        const uint32_ badd = (e0 >= E_) ? (uint32_)E_ : 0u;

        // 10 wave-wide 512 B gathers (uint2 per lane), all independent
        const uint2 SA = xt2[(((uint32_)e0)     << 6) + lane];
        const uint2 SB = xt2[(((uint32_)e0 + 1) << 6) + lane];
        const uint2 A1 = xt2[((badd + (uint32_)gA.x) << 6) + lane];
        const uint2 A2 = xt2[((badd + (uint32_)gA.y) << 6) + lane];
        const uint2 A3 = xt2[((badd + (uint32_)gA.z) << 6) + lane];
        const uint2 A4 = xt2[((badd + (uint32_)gA.w) << 6) + lane];
        const uint2 B1 = xt2[((badd + (uint32_)gB.x) << 6) + lane];
        const uint2 B2 = xt2[((badd + (uint32_)gB.y) << 6) + lane];
        const uint2 B3 = xt2[((badd + (uint32_)gB.z) << 6) + lane];
        const uint2 B4 = xt2[((badd + (uint32_)gB.w) << 6) + lane];

        // ---- edge A ----
        float rA0, rA1, rA2;
        {
            v4f a0 = bp4(SA);
            v4f a1 = bp4(A1), a2 = bp4(A2), a3 = bp4(A3), a4 = bp4(A4);
            v4f s1 = a1 + a3, s2 = a2 + a4;
            v4f d1 = vabs4(a1 - a3), d2 = vabs4(a2 - a4);
            v4f t0 = w[0][0] * a0, t1 = w[1][0] * a0, t2 = w[2][0] * a0;
            t0 += w[0][1] * s1; t1 += w[1][1] * s1; t2 += w[2][1] * s1;
            t0 += w[0][2] * s2; t1 += w[1][2] * s2; t2 += w[2][2] * s2;
            t0 += w[0][3] * d1; t1 += w[1][3] * d1; t2 += w[2][3] * d1;
            t0 += w[0][4] * d2; t1 += w[1][4] * d2; t2 += w[2][4] * d2;
            rA0 = (t0.x + t0.y) + (t0.z + t0.w);
            rA1 = (t1.x + t1.y) + (t1.z + t1.w);
            rA2 = (t2.x + t2.y) + (t2.z + t2.w);
        }
        // ---- edge B ----
        float rB0, rB1, rB2;
        {
            v4f a0 = bp4(SB);
            v4f a1 = bp4(B1), a2 = bp4(B2), a3 = bp4(B3), a4 = bp4(B4);
            v4f s1 = a1 + a3, s2 = a2 + a4;
            v4f d1 = vabs4(a1 - a3), d2 = vabs4(a2 - a4);
            v4f t0 = w[0][0] * a0, t1 = w[1][0] * a0, t2 = w[2][0] * a0;
            t0 += w[0][1] * s1; t1 += w[1][1] * s1; t2 += w[2][1] * s1;
            t0 += w[0][2] * s2; t1 += w[1][2] * s2; t2 += w[2][2] * s2;
            t0 += w[0][3] * d1; t1 += w[1][3] * d1; t2 += w[2][3] * d1;
            t0 += w[0][4] * d2; t1 += w[1][4] * d2; t2 += w[2][4] * d2;
            rB0 = (t0.x + t0.y) + (t0.z + t0.w);
            rB1 = (t1.x + t1.y) + (t1.z + t1.w);
            rB2 = (t2.x + t2.y) + (t2.z + t2.w);
        }

        // full 64-lane reduce (both tensors + all channels), A/B interleaved
        rA0 = swz_add(rA0, 16); rB0 = swz_add(rB0, 16);
        rA1 = swz_add(rA1, 16); rB1 = swz_add(rB1, 16);
        rA2 = swz_add(rA2, 16); rB2 = swz_add(rB2, 16);
        rA0 += __shfl_xor(rA0, 32, 64); rB0 += __shfl_xor(rB0, 32, 64);
        rA1 += __shfl_xor(rA1, 32, 64); rB1 += __shfl_xor(rB1, 32, 64);
        rA2 += __shfl_xor(rA2, 32, 64); rB2 += __shfl_xor(rB2, 32, 64);

        float vA = is0 ? rA0 : (is1 ? rA1 : rA2);
        float vB = is0 ? rB0 : (is1 ? rB1 : rB2);
        vA = swz_add(vA, 1); vB = swz_add(vB, 1);
        vA = swz_add(vA, 2); vB = swz_add(vB, 2);
        vA = swz_add(vA, 4); vB = swz_add(vB, 4);
        vA = swz_add(vA, 8); vB = swz_add(vB, 8);

        if (writer) {
            const int bb = (e0 >= E_) ? 1 : 0;
            const int ee = e0 - (bb ? E_ : 0);
            float2 st; st.x = vA + cj; st.y = vB + cj;
            *(float2*)(obase + (bb ? 3 * E_ : 0) + ee) = st;   // ee even -> aligned
        }
    }
}

extern "C" void kernel_launch(void* const* d_in, const int* in_sizes, int n_in,
                              void* d_out, int out_size, void* d_ws, size_t ws_size,
                              hipStream_t stream) {
    const float* x0       = (const float*)d_in[0];
    const float* x1       = (const float*)d_in[1];
    const int*   gemm     = (const int*)d_in[2];
    const float* Wa_local = (const float*)d_in[3];
    const float* ba_local = (const float*)d_in[4];
    const float* Wb_local = (const float*)d_in[5];
    const float* bb_local = (const float*)d_in[6];
    const float* Wa_tri   = (const float*)d_in[7];
    const float* ba_tri   = (const float*)d_in[8];
    const float* Wb_tri   = (const float*)d_in[9];
    const float* bb_tri   = (const float*)d_in[10];
    const float* Wa_fuse  = (const float*)d_in[11];
    const float* ba_fuse  = (const float*)d_in[12];
    const float* Wb_fuse  = (const float*)d_in[13];
    const float* bb_fuse  = (const float*)d_in[14];
    float* out = (float*)d_out;

    ushort_* xt  = (ushort_*)d_ws;                       // [B][E][2][C] bf16
    float*   Vw  = (float*)(xt + (size_t)B_ * E_ * 2 * C_);
    float*   cst = Vw + 2 * 3 * 5 * C_;

    hipLaunchKernelGGL(prep_kernel, dim3(61 + 8 * (E_ / 32)), dim3(256), 0, stream,
                       x0, x1,
                       Wa_local, ba_local, Wb_local, bb_local,
                       Wa_tri, ba_tri, Wb_tri, bb_tri,
                       Wa_fuse, ba_fuse, Wb_fuse, bb_fuse, xt, Vw, cst);

    hipLaunchKernelGGL(mesh_fused_kernel, dim3(2048), dim3(256), 0, stream,
                       (const uint2*)xt, gemm, Vw, cst, out);
}